// Round 5
// baseline (647.977 us; speedup 1.0000x reference)
//
#include <hip/hip_runtime.h>
#include <hip/hip_bf16.h>

typedef __hip_bfloat16 bf16;
using f32x4  = __attribute__((ext_vector_type(4))) float;
using short8 = __attribute__((ext_vector_type(8))) short;

#define B_ 4
#define T_ 1024
#define S_ 32
#define D_ 512
#define M_ (B_*T_)   // 4096 rows (b*T+t)
#define E_ (2*D_)    // 1024 concat dim

// async global->LDS, 16B per lane; LDS dest must be wave-uniform (HW adds lane*16)
__device__ __forceinline__ void gload_lds16(const void* g, void* l) {
  __builtin_amdgcn_global_load_lds(
      (const __attribute__((address_space(1))) unsigned int*)g,
      (__attribute__((address_space(3))) unsigned int*)l, 16, 0, 0);
}

__device__ __forceinline__ float bfbits(unsigned short u) {
  return __uint_as_float(((unsigned)u) << 16);
}

// ---------------- elementwise prep ----------------
__global__ void cast_bf16_k(const float* __restrict__ in, bf16* __restrict__ out, int n) {
  int i = blockIdx.x * blockDim.x + threadIdx.x;
  if (i < n) out[i] = __float2bfloat16(in[i]);
}

// cur2[i][e] = e<512 ? real[i][e] : imag[i][e-512], cast bf16
__global__ void concat_cast_k(const float* __restrict__ re, const float* __restrict__ im,
                              bf16* __restrict__ out) {
  int g = blockIdx.x * blockDim.x + threadIdx.x;   // 0 .. M_*E_-1
  int i = g >> 10, e = g & 1023;
  float v = (e < D_) ? re[(size_t)i * D_ + e] : im[(size_t)i * D_ + (e - D_)];
  out[g] = __float2bfloat16(v);
}

// out[C][R] = cast(in[R][C]^T)
__global__ __launch_bounds__(256)
void transpose_cast_k(const float* __restrict__ in, bf16* __restrict__ out, int R, int C) {
  __shared__ float t[32][33];
  int tx = threadIdx.x & 31, ty = threadIdx.x >> 5;   // ty 0..7
  int r0 = blockIdx.y * 32, c0 = blockIdx.x * 32;
#pragma unroll
  for (int j = 0; j < 4; ++j)
    t[ty + 8 * j][tx] = in[(size_t)(r0 + ty + 8 * j) * C + c0 + tx];
  __syncthreads();
#pragma unroll
  for (int j = 0; j < 4; ++j)
    out[(size_t)(c0 + ty + 8 * j) * R + r0 + tx] = __float2bfloat16(t[tx][ty + 8 * j]);
}

// ---------------- bf16 MFMA GEMM, C = A[M,K] * B^T (B stored [N][K]) ----------------
// 128x128 tile, BK=64, 4 waves (2x2), each wave 64x64 = 4x4 frags of 16x16x32.
// MODE 0: out bf16 = acc + bias                       (Q projection)
// MODE 1: out bf16 = acc                              (Q' = Q @ kW^T)
// MODE 2: interleaved complex epilogue (out_size==4M world)
// MODE 3: planar real-only epilogue    (out_size==2M world; grid.x covers cols<512)
template<int MODE>
__global__ __launch_bounds__(256)
void gemm_bt(const bf16* __restrict__ A, const bf16* __restrict__ Bm,
             int M, int N, int K,
             const float* __restrict__ bias,
             bf16* __restrict__ outB,
             const float* __restrict__ curR, const float* __restrict__ curI,
             float* __restrict__ outC) {
  __shared__ bf16 sA[128 * 64];
  __shared__ bf16 sB[128 * 64];
  const int tid = threadIdx.x, lane = tid & 63, wid = tid >> 6;
  const int bm = blockIdx.y, bn = blockIdx.x;
  const int wm = wid >> 1, wn = wid & 1;
  const int r16 = lane & 15, h = lane >> 4;

  f32x4 acc[4][4];
#pragma unroll
  for (int m = 0; m < 4; ++m)
#pragma unroll
    for (int n = 0; n < 4; ++n) acc[m][n] = (f32x4){0.f, 0.f, 0.f, 0.f};

  for (int k0 = 0; k0 < K; k0 += 64) {
    __syncthreads();   // prior compute done before overwriting LDS
#pragma unroll
    for (int is = 0; is < 4; ++is) {
      int u = wid * 256 + is * 64 + lane;       // 16B unit index (1024 units per tile)
      int row = u >> 3, c8 = (u & 7) * 8;
      char* dA = (char*)sA + (wid * 256 + is * 64) * 16;  // wave-uniform
      char* dB = (char*)sB + (wid * 256 + is * 64) * 16;
      gload_lds16(A  + (size_t)(bm * 128 + row) * K + k0 + c8, dA);
      gload_lds16(Bm + (size_t)(bn * 128 + row) * K + k0 + c8, dB);
    }
    __syncthreads();   // loads landed
#pragma unroll
    for (int kk = 0; kk < 2; ++kk) {
      short8 a[4], b[4];
#pragma unroll
      for (int m = 0; m < 4; ++m)
        a[m] = *(const short8*)(sA + (wm * 64 + m * 16 + r16) * 64 + kk * 32 + h * 8);
#pragma unroll
      for (int n = 0; n < 4; ++n)
        b[n] = *(const short8*)(sB + (wn * 64 + n * 16 + r16) * 64 + kk * 32 + h * 8);
#pragma unroll
      for (int m = 0; m < 4; ++m)
#pragma unroll
        for (int n = 0; n < 4; ++n)
          acc[m][n] = __builtin_amdgcn_mfma_f32_16x16x32_bf16(a[m], b[n], acc[m][n], 0, 0, 0);
    }
  }

#pragma unroll
  for (int m = 0; m < 4; ++m)
#pragma unroll
    for (int n = 0; n < 4; ++n) {
      int col = bn * 128 + wn * 64 + n * 16 + r16;
#pragma unroll
      for (int r = 0; r < 4; ++r) {
        int row = bm * 128 + wm * 64 + m * 16 + h * 4 + r;
        float v = acc[m][n][r];
        if (MODE == 0) {
          outB[(size_t)row * N + col] = __float2bfloat16(v + bias[col]);
        } else if (MODE == 1) {
          outB[(size_t)row * N + col] = __float2bfloat16(v);
        } else if (MODE == 2) {
          float vv = v + bias[col];
          if (col < D_)
            outC[(size_t)row * E_ + 2 * col] = curR[(size_t)row * D_ + col] + 0.1f * vv;
          else
            outC[(size_t)row * E_ + 2 * (col - D_) + 1] =
                curI[(size_t)row * D_ + (col - D_)] + 0.1f * vv;
        } else {  // MODE 3: planar real only; col < 512 guaranteed by grid
          float vv = v + bias[col];
          outC[(size_t)row * D_ + col] = curR[(size_t)row * D_ + col] + 0.1f * vv;
        }
      }
    }
}

// ---------------- qkb[i] = Q[i,:] . kb ----------------
__global__ __launch_bounds__(256)
void qkb_k(const bf16* __restrict__ Qb, const float* __restrict__ kb, float* __restrict__ qkb) {
  int lane = threadIdx.x & 63;
  int row = blockIdx.x * 4 + (threadIdx.x >> 6);
  float p = 0.f;
#pragma unroll
  for (int k = 0; k < 8; ++k) {
    int d = lane + 64 * k;
    p += __bfloat162float(Qb[(size_t)row * D_ + d]) * kb[d];
  }
#pragma unroll
  for (int off = 32; off > 0; off >>= 1) p += __shfl_xor(p, off);
  if (lane == 0) qkb[row] = p;
}

// ---------------- fused attention over S=32 slots, single H pass ----------------
// Block = 1024 threads per (b,t) row. Thread t: u=t&255 owns elements 4u..4u+3,
// g=t>>8 owns slots 8g..8g+7. H held entirely in registers (8 x float4).
__global__ __launch_bounds__(1024)
void attn_k(const float* __restrict__ histR, const float* __restrict__ histI,
            const bf16* __restrict__ Qp, const float* __restrict__ qkb,
            const float* __restrict__ conf, bf16* __restrict__ Hw) {
  __shared__ float scp[S_][4];      // per-slot wave partials
  __shared__ float ctxp[4][E_];     // per-slot-group ctx partials (16 KB)
  const int i = blockIdx.x;
  const int tid = threadIdx.x;
  const int u = tid & 255, g = tid >> 8;       // element group / slot group
  const int lane = tid & 63, wg = (tid >> 6) & 3;
  const int s0 = 8 * g;

  // Q' fragment (4 bf16)
  float q[4];
  {
    ushort4 qv = *(const ushort4*)((const unsigned short*)Qp + (size_t)i * E_ + 4 * u);
    q[0] = bfbits(qv.x); q[1] = bfbits(qv.y); q[2] = bfbits(qv.z); q[3] = bfbits(qv.w);
  }

  // H fragments: slot s0+si, elements 4u..4u+3 (all within one half)
  const float* base = (u < 128)
      ? histR + (size_t)i * S_ * D_ + 4 * u
      : histI + (size_t)i * S_ * D_ + 4 * u - D_;
  float4 H4[8];
#pragma unroll
  for (int si = 0; si < 8; ++si)
    H4[si] = *(const float4*)(base + (size_t)(s0 + si) * D_);

  // phase 1: score partials (wave (g,wg) covers slots s0..s0+7, element quarter wg)
#pragma unroll
  for (int si = 0; si < 8; ++si) {
    float p = q[0] * H4[si].x + q[1] * H4[si].y + q[2] * H4[si].z + q[3] * H4[si].w;
#pragma unroll
    for (int off = 32; off > 0; off >>= 1) p += __shfl_xor(p, off);
    if (lane == 0) scp[s0 + si][wg] = p;
  }
  __syncthreads();

  // softmax (redundant per thread; LDS reads are broadcasts)
  const float cf = conf[i], add = qkb[i];
  const float scale = 0.044194173824159216f;  // 512^-0.5
  float mx = -1e30f;
#pragma unroll
  for (int s = 0; s < S_; ++s) {
    float v = (scp[s][0] + scp[s][1] + scp[s][2] + scp[s][3] + add) * scale * cf;
    mx = fmaxf(mx, v);
  }
  float l = 0.f;
#pragma unroll
  for (int s = 0; s < S_; ++s) {
    float v = (scp[s][0] + scp[s][1] + scp[s][2] + scp[s][3] + add) * scale * cf;
    l += __expf(v - mx);
  }
  const float inv = 1.f / l;
  // own-slot weights with compile-time indexing (avoid runtime-indexed reg array)
  float wv[8];
#pragma unroll
  for (int si = 0; si < 8; ++si) {
    int s = s0 + si;
    float v = (scp[s][0] + scp[s][1] + scp[s][2] + scp[s][3] + add) * scale * cf;
    wv[si] = __expf(v - mx);
  }

  // phase 2: weighted sum over this thread's 8 slots
  f32x4 c = (f32x4){0.f, 0.f, 0.f, 0.f};
#pragma unroll
  for (int si = 0; si < 8; ++si) {
    c[0] += wv[si] * H4[si].x;
    c[1] += wv[si] * H4[si].y;
    c[2] += wv[si] * H4[si].z;
    c[3] += wv[si] * H4[si].w;
  }
  *(f32x4*)&ctxp[g][4 * u] = c;
  __syncthreads();

  float r = (ctxp[0][tid] + ctxp[1][tid] + ctxp[2][tid] + ctxp[3][tid]) * inv;
  Hw[(size_t)i * E_ + tid] = __float2bfloat16(r);
}

extern "C" void kernel_launch(void* const* d_in, const int* in_sizes, int n_in,
                              void* d_out, int out_size, void* d_ws, size_t ws_size,
                              hipStream_t stream) {
  const float* histR = (const float*)d_in[0];
  const float* histI = (const float*)d_in[1];
  const float* curR  = (const float*)d_in[2];
  const float* curI  = (const float*)d_in[3];
  const float* conf  = (const float*)d_in[4];
  const float* qW    = (const float*)d_in[5];
  const float* qb    = (const float*)d_in[6];
  const float* kW    = (const float*)d_in[7];
  const float* kb    = (const float*)d_in[8];
  const float* vW    = (const float*)d_in[9];
  const float* vb    = (const float*)d_in[10];
  float* out = (float*)d_out;

  // ALL scratch in d_ws (24.02 MiB; round-0 ran 40 MiB of d_ws fault-free).
  // d_out is written ONLY by the final GEMM.
  char* ws = (char*)d_ws;
  bf16*  cur2b = (bf16*)ws;                        // 8 MiB [4096][1024]; reused as Hw
  bf16*  Hwb   = cur2b;                            //   (cur2b dead after Q GEMM)
  bf16*  vWT   = (bf16*)(ws + ( 8u << 20));        // 2 MiB [1024][1024] = vW^T
  bf16*  Qb    = (bf16*)(ws + (10u << 20));        // 4 MiB [4096][512]
  bf16*  Qpb   = (bf16*)(ws + (14u << 20));        // 8 MiB [4096][1024]
  bf16*  qWT   = (bf16*)(ws + (22u << 20));        // 1 MiB [512][1024]  = qW^T
  bf16*  kWb   = (bf16*)(ws + (23u << 20));        // 1 MiB [1024][512]  = kW
  float* qkbv  = (float*)(ws + (24u << 20));       // 16 KiB

  // prep
  concat_cast_k<<<(M_ * E_) / 256, 256, 0, stream>>>(curR, curI, cur2b);
  cast_bf16_k<<<(E_ * D_) / 256, 256, 0, stream>>>(kW, kWb, E_ * D_);
  transpose_cast_k<<<dim3(D_ / 32, E_ / 32), 256, 0, stream>>>(qW, qWT, E_, D_);
  transpose_cast_k<<<dim3(E_ / 32, E_ / 32), 256, 0, stream>>>(vW, vWT, E_, E_);

  // Q = cur2 @ qW + qb          [4096,512] bf16
  gemm_bt<0><<<dim3(D_ / 128, M_ / 128), 256, 0, stream>>>(
      cur2b, qWT, M_, D_, E_, qb, Qb, nullptr, nullptr, nullptr);
  // qkb = Q . kb
  qkb_k<<<M_ / 4, 256, 0, stream>>>(Qb, kb, qkbv);
  // Q' = Q @ kW^T               [4096,1024] bf16
  gemm_bt<1><<<dim3(E_ / 128, M_ / 128), 256, 0, stream>>>(
      Qb, kWb, M_, E_, D_, nullptr, Qpb, nullptr, nullptr, nullptr);
  // attention: Hw = softmax((Q'.H + qkb)*scale*conf) . H   [4096,1024] bf16
  attn_k<<<M_, 1024, 0, stream>>>(histR, histI, Qpb, qkbv, conf, Hwb);

  // Final: out = current + 0.1*(Hw @ vW + vb).
  // Output layout decided at runtime from out_size:
  //   out_size == M_*D_   (2M): planar REAL ONLY [4,1024,512] (complex->f32 cast world)
  //   otherwise           (4M): interleaved complex64 as float pairs
  if (out_size == M_ * D_) {
    gemm_bt<3><<<dim3(D_ / 128, M_ / 128), 256, 0, stream>>>(
        Hwb, vWT, M_, E_, E_, vb, nullptr, curR, curI, out);
  } else {
    gemm_bt<2><<<dim3(E_ / 128, M_ / 128), 256, 0, stream>>>(
        Hwb, vWT, M_, E_, E_, vb, nullptr, curR, curI, out);
  }
}

// Round 7
// 601.638 us; speedup vs baseline: 1.0770x; 1.0770x over previous
//
#include <hip/hip_runtime.h>
#include <hip/hip_bf16.h>

typedef __hip_bfloat16 bf16;
using f32x4  = __attribute__((ext_vector_type(4))) float;
using short8 = __attribute__((ext_vector_type(8))) short;

#define B_ 4
#define T_ 1024
#define S_ 32
#define D_ 512
#define M_ (B_*T_)   // 4096 rows (b*T+t)
#define E_ (2*D_)    // 1024 concat dim

// async global->LDS, 16B per lane; LDS dest must be wave-uniform (HW adds lane*16)
__device__ __forceinline__ void gload_lds16(const void* g, void* l) {
  __builtin_amdgcn_global_load_lds(
      (const __attribute__((address_space(1))) unsigned int*)g,
      (__attribute__((address_space(3))) unsigned int*)l, 16, 0, 0);
}

__device__ __forceinline__ float bfbits(unsigned short u) {
  return __uint_as_float(((unsigned)u) << 16);
}

// ---------------- elementwise prep ----------------
// cur2[i][e] = e<512 ? real[i][e] : imag[i][e-512], cast bf16
__global__ void concat_cast_k(const float* __restrict__ re, const float* __restrict__ im,
                              bf16* __restrict__ out) {
  int g = blockIdx.x * blockDim.x + threadIdx.x;   // 0 .. M_*E_-1
  int i = g >> 10, e = g & 1023;
  float v = (e < D_) ? re[(size_t)i * D_ + e] : im[(size_t)i * D_ + (e - D_)];
  out[g] = __float2bfloat16(v);
}

// cast qW and kW (each n elems) to bf16 in one launch
__global__ void cast2_k(const float* __restrict__ a, const float* __restrict__ b,
                        bf16* __restrict__ ab, bf16* __restrict__ bb, int n) {
  int i = blockIdx.x * blockDim.x + threadIdx.x;
  if (i < n) ab[i] = __float2bfloat16(a[i]);
  else if (i < 2 * n) bb[i - n] = __float2bfloat16(b[i - n]);
}

// out[C][R] = cast(in[R][C]^T)
__global__ __launch_bounds__(256)
void transpose_cast_k(const float* __restrict__ in, bf16* __restrict__ out, int R, int C) {
  __shared__ float t[32][33];
  int tx = threadIdx.x & 31, ty = threadIdx.x >> 5;   // ty 0..7
  int r0 = blockIdx.y * 32, c0 = blockIdx.x * 32;
#pragma unroll
  for (int j = 0; j < 4; ++j)
    t[ty + 8 * j][tx] = in[(size_t)(r0 + ty + 8 * j) * C + c0 + tx];
  __syncthreads();
#pragma unroll
  for (int j = 0; j < 4; ++j)
    out[(size_t)(c0 + ty + 8 * j) * R + r0 + tx] = __float2bfloat16(t[tx][ty + 8 * j]);
}

// blocks 0..255:  u[e]  = qW_row_e . kb   (e = blk*4+wave)
// blocks 256..511: v2[e] = kW_row_e . qb
__global__ __launch_bounds__(256)
void uvec_k(const float* __restrict__ qW, const float* __restrict__ kb,
            const float* __restrict__ kW, const float* __restrict__ qb,
            float* __restrict__ u, float* __restrict__ v2) {
  int lane = threadIdx.x & 63, w = threadIdx.x >> 6;
  int which = blockIdx.x >= 256;
  int e = ((blockIdx.x & 255) << 2) + w;
  const float* src = which ? kW : qW;
  const float* vec = which ? qb : kb;
  float p = 0.f;
#pragma unroll
  for (int k = 0; k < 8; ++k) {
    int d = lane + 64 * k;
    p += src[(size_t)e * D_ + d] * vec[d];
  }
#pragma unroll
  for (int off = 32; off > 0; off >>= 1) p += __shfl_xor(p, off);
  if (lane == 0) (which ? v2 : u)[e] = p;
}

// qkb[i] = cur2[i,:].u + qb.kb   (wave per row; combined reduce)
__global__ __launch_bounds__(256)
void qkb_k(const bf16* __restrict__ cur2, const float* __restrict__ u,
           const float* __restrict__ qb, const float* __restrict__ kb,
           float* __restrict__ qkb) {
  int lane = threadIdx.x & 63;
  int row = blockIdx.x * 4 + (threadIdx.x >> 6);
  float p = 0.f;
#pragma unroll
  for (int k = 0; k < 16; ++k) {
    int d = lane + 64 * k;
    p += __bfloat162float(cur2[(size_t)row * E_ + d]) * u[d];
  }
#pragma unroll
  for (int k = 0; k < 8; ++k) {     // qb.kb partial folded into same reduce
    int d = lane + 64 * k;
    p += qb[d] * kb[d];
  }
#pragma unroll
  for (int off = 32; off > 0; off >>= 1) p += __shfl_xor(p, off);
  if (lane == 0) qkb[row] = p;
}

// ---------------- bf16 MFMA GEMM, C = A[M,K] * B^T (B stored [N][K]) ----------------
// 64x64 tile, BK=64, 4 waves (2x2), each wave 32x32 = 2x2 frags of 16x16x32.
// MODE 0: out bf16 = acc + bias   MODE 1: out bf16 = acc
// MODE 2: interleaved complex epilogue   MODE 3: planar real-only epilogue
template<int MODE>
__global__ __launch_bounds__(256)
void gemm64(const bf16* __restrict__ A, const bf16* __restrict__ Bm,
            int M, int N, int K,
            const float* __restrict__ bias,
            bf16* __restrict__ outB,
            const float* __restrict__ curR, const float* __restrict__ curI,
            float* __restrict__ outC) {
  __shared__ bf16 sA[64 * 64];
  __shared__ bf16 sB[64 * 64];
  const int tid = threadIdx.x, lane = tid & 63, wid = tid >> 6;
  const int bm = blockIdx.y, bn = blockIdx.x;
  const int wm = wid >> 1, wn = wid & 1;
  const int r16 = lane & 15, h = lane >> 4;

  f32x4 acc[2][2];
#pragma unroll
  for (int m = 0; m < 2; ++m)
#pragma unroll
    for (int n = 0; n < 2; ++n) acc[m][n] = (f32x4){0.f, 0.f, 0.f, 0.f};

  for (int k0 = 0; k0 < K; k0 += 64) {
    __syncthreads();
#pragma unroll
    for (int is = 0; is < 2; ++is) {
      int unit = is * 256 + tid;                 // 512 x 16B units per 8KB tile
      int row = unit >> 3, c8 = (unit & 7) * 8;
      char* dA = (char*)sA + (is * 256 + wid * 64) * 16;   // wave-uniform
      char* dB = (char*)sB + (is * 256 + wid * 64) * 16;
      gload_lds16(A  + (size_t)(bm * 64 + row) * K + k0 + c8, dA);
      gload_lds16(Bm + (size_t)(bn * 64 + row) * K + k0 + c8, dB);
    }
    __syncthreads();
#pragma unroll
    for (int kk = 0; kk < 2; ++kk) {
      short8 a[2], b[2];
#pragma unroll
      for (int m = 0; m < 2; ++m)
        a[m] = *(const short8*)(sA + (wm * 32 + m * 16 + r16) * 64 + kk * 32 + h * 8);
#pragma unroll
      for (int n = 0; n < 2; ++n)
        b[n] = *(const short8*)(sB + (wn * 32 + n * 16 + r16) * 64 + kk * 32 + h * 8);
#pragma unroll
      for (int m = 0; m < 2; ++m)
#pragma unroll
        for (int n = 0; n < 2; ++n)
          acc[m][n] = __builtin_amdgcn_mfma_f32_16x16x32_bf16(a[m], b[n], acc[m][n], 0, 0, 0);
    }
  }

#pragma unroll
  for (int m = 0; m < 2; ++m)
#pragma unroll
    for (int n = 0; n < 2; ++n) {
      int col = bn * 64 + wn * 32 + n * 16 + r16;
#pragma unroll
      for (int r = 0; r < 4; ++r) {
        int row = bm * 64 + wm * 32 + m * 16 + h * 4 + r;
        float v = acc[m][n][r];
        if (MODE == 0) {
          outB[(size_t)row * N + col] = __float2bfloat16(v + bias[col]);
        } else if (MODE == 1) {
          outB[(size_t)row * N + col] = __float2bfloat16(v);
        } else if (MODE == 2) {
          float vv = v + bias[col];
          if (col < D_)
            outC[(size_t)row * E_ + 2 * col] = curR[(size_t)row * D_ + col] + 0.1f * vv;
          else
            outC[(size_t)row * E_ + 2 * (col - D_) + 1] =
                curI[(size_t)row * D_ + (col - D_)] + 0.1f * vv;
        } else {  // MODE 3: planar real only; col < 512 guaranteed by grid
          float vv = v + bias[col];
          outC[(size_t)row * D_ + col] = curR[(size_t)row * D_ + col] + 0.1f * vv;
        }
      }
    }
}

// ---------------- fused attention over S=32 slots, single H pass ----------------
// Block = 512 threads per (b,t). Thread: u=tid&127 owns elems 8u..8u+7,
// g=tid>>7 owns slots 8g..8g+7.  H in regs: 16 independent float4 loads (MLP).
// scores: in-thread 8-elem dot -> 6-step shuffle -> scp[32][2] -> barrier.
// softmax recomputed from LDS per pass (no runtime-indexed reg arrays — rule #20).
__global__ __launch_bounds__(512)
void attn_k(const float* __restrict__ histR, const float* __restrict__ histI,
            const bf16* __restrict__ Qp, const float* __restrict__ qkb,
            const float* __restrict__ conf, bf16* __restrict__ Hw) {
  __shared__ float scp[S_][2];
  __shared__ float ctxp[4][E_];     // 16 KB
  const int i = blockIdx.x;
  const int tid = threadIdx.x;
  const int u = tid & 127, g = tid >> 7;
  const int lane = tid & 63, half = u >> 6;
  const int s0 = 8 * g;

  // H loads first: 16 independent float4 (elems 8u..8u+7 of slots s0..s0+7)
  const float* base = (u < 64)
      ? histR + (size_t)i * S_ * D_ + 8 * u
      : histI + (size_t)i * S_ * D_ + 8 * u - D_;
  float4 hp[16];
#pragma unroll
  for (int si = 0; si < 8; ++si) {
    hp[2 * si]     = *(const float4*)(base + (size_t)(s0 + si) * D_);
    hp[2 * si + 1] = *(const float4*)(base + (size_t)(s0 + si) * D_ + 4);
  }

  // Q' fragment (8 bf16 = 16B)
  float q[8];
  {
    ushort4 qa = *(const ushort4*)((const unsigned short*)Qp + (size_t)i * E_ + 8 * u);
    ushort4 qc = *(const ushort4*)((const unsigned short*)Qp + (size_t)i * E_ + 8 * u + 4);
    q[0] = bfbits(qa.x); q[1] = bfbits(qa.y); q[2] = bfbits(qa.z); q[3] = bfbits(qa.w);
    q[4] = bfbits(qc.x); q[5] = bfbits(qc.y); q[6] = bfbits(qc.z); q[7] = bfbits(qc.w);
  }

  // phase 1: score partials (8 independent shuffle chains)
#pragma unroll
  for (int si = 0; si < 8; ++si) {
    float p = q[0] * hp[2*si].x + q[1] * hp[2*si].y + q[2] * hp[2*si].z + q[3] * hp[2*si].w
            + q[4] * hp[2*si+1].x + q[5] * hp[2*si+1].y + q[6] * hp[2*si+1].z + q[7] * hp[2*si+1].w;
#pragma unroll
    for (int off = 32; off > 0; off >>= 1) p += __shfl_xor(p, off);
    if (lane == 0) scp[s0 + si][half] = p;
  }
  __syncthreads();

  // softmax: recompute logits from scp (LDS broadcast) in each pass — no
  // runtime-indexed register arrays (rule #20).
  const float cf = conf[i], add = qkb[i];
  const float scale = 0.044194173824159216f;  // 512^-0.5
  float mx = -1e30f;
#pragma unroll
  for (int s = 0; s < S_; ++s)
    mx = fmaxf(mx, (scp[s][0] + scp[s][1] + add) * scale * cf);
  float l = 0.f;
#pragma unroll
  for (int s = 0; s < S_; ++s)
    l += __expf((scp[s][0] + scp[s][1] + add) * scale * cf - mx);
  const float inv = 1.f / l;
  float wv[8];
#pragma unroll
  for (int si = 0; si < 8; ++si)
    wv[si] = __expf((scp[s0 + si][0] + scp[s0 + si][1] + add) * scale * cf - mx);

  // phase 2: weighted sum over own 8 slots
  f32x4 c0 = (f32x4){0.f,0.f,0.f,0.f}, c1 = (f32x4){0.f,0.f,0.f,0.f};
#pragma unroll
  for (int si = 0; si < 8; ++si) {
    c0[0] += wv[si] * hp[2*si].x;  c0[1] += wv[si] * hp[2*si].y;
    c0[2] += wv[si] * hp[2*si].z;  c0[3] += wv[si] * hp[2*si].w;
    c1[0] += wv[si] * hp[2*si+1].x; c1[1] += wv[si] * hp[2*si+1].y;
    c1[2] += wv[si] * hp[2*si+1].z; c1[3] += wv[si] * hp[2*si+1].w;
  }
  *(f32x4*)&ctxp[g][8 * u] = c0;
  *(f32x4*)&ctxp[g][8 * u + 4] = c1;
  __syncthreads();

  // final: each thread 2 elements
  int e = 2 * tid;
  float r0 = (ctxp[0][e] + ctxp[1][e] + ctxp[2][e] + ctxp[3][e]) * inv;
  float r1 = (ctxp[0][e+1] + ctxp[1][e+1] + ctxp[2][e+1] + ctxp[3][e+1]) * inv;
  bf16* dst = Hw + (size_t)i * E_ + e;
  dst[0] = __float2bfloat16(r0);
  dst[1] = __float2bfloat16(r1);
}

extern "C" void kernel_launch(void* const* d_in, const int* in_sizes, int n_in,
                              void* d_out, int out_size, void* d_ws, size_t ws_size,
                              hipStream_t stream) {
  const float* histR = (const float*)d_in[0];
  const float* histI = (const float*)d_in[1];
  const float* curR  = (const float*)d_in[2];
  const float* curI  = (const float*)d_in[3];
  const float* conf  = (const float*)d_in[4];
  const float* qW    = (const float*)d_in[5];
  const float* qb    = (const float*)d_in[6];
  const float* kW    = (const float*)d_in[7];
  const float* kb    = (const float*)d_in[8];
  const float* vW    = (const float*)d_in[9];
  const float* vb    = (const float*)d_in[10];
  float* out = (float*)d_out;

  // d_ws scratch (~30.1 MiB; 40 MiB ran fault-free in round 0)
  char* ws = (char*)d_ws;
  bf16*  cur2b = (bf16*)ws;                          // 8 MiB [4096][1024]
  bf16*  Qpb   = (bf16*)(ws + ( 8u << 20));          // 8 MiB [4096][1024]
  bf16*  Hwb   = (bf16*)(ws + (16u << 20));          // 8 MiB [4096][1024]
  bf16*  Wkq   = (bf16*)(ws + (24u << 20));          // 2 MiB [e2=1024][e1=1024]
  bf16*  vWT   = (bf16*)(ws + (26u << 20));          // 2 MiB [1024][1024] = vW^T
  bf16*  qWb   = (bf16*)(ws + (28u << 20));          // 1 MiB [1024][512]
  bf16*  kWb   = (bf16*)(ws + (29u << 20));          // 1 MiB [1024][512]
  float* uvec  = (float*)(ws + (30u << 20));         // 4 KiB  u = qW@kb
  float* v2vec = (float*)(ws + (30u << 20) + 16384); // 4 KiB  v2 = kW@qb
  float* qkbv  = (float*)(ws + (30u << 20) + 32768); // 16 KiB

  // prep (independent)
  concat_cast_k<<<(M_ * E_) / 256, 256, 0, stream>>>(curR, curI, cur2b);
  cast2_k<<<(2 * E_ * D_) / 256, 256, 0, stream>>>(qW, kW, qWb, kWb, E_ * D_);
  transpose_cast_k<<<dim3(E_ / 32, E_ / 32), 256, 0, stream>>>(vW, vWT, E_, E_);
  uvec_k<<<512, 256, 0, stream>>>(qW, kb, kW, qb, uvec, v2vec);

  // Wkq[e2][e1] = kW_row_e2 . qW_row_e1   (= (qW@kW^T)^T, the B-layout for Q')
  gemm64<1><<<dim3(E_ / 64, E_ / 64), 256, 0, stream>>>(
      kWb, qWb, E_, E_, D_, nullptr, Wkq, nullptr, nullptr, nullptr);
  // qkb[i] = cur2 . u + qb.kb
  qkb_k<<<M_ / 4, 256, 0, stream>>>(cur2b, uvec, qb, kb, qkbv);
  // Q' = cur2 @ Wkq^T + v2     [4096,1024] bf16
  gemm64<0><<<dim3(E_ / 64, M_ / 64), 256, 0, stream>>>(
      cur2b, Wkq, M_, E_, E_, v2vec, Qpb, nullptr, nullptr, nullptr);
  // attention: Hw = softmax((Q'.H + qkb)*scale*conf) . H   [4096,1024] bf16
  attn_k<<<M_, 512, 0, stream>>>(histR, histI, Qpb, qkbv, conf, Hwb);

  // Final: out = current + 0.1*(Hw @ vW + vb)
  if (out_size == M_ * D_) {   // planar real-only world
    gemm64<3><<<dim3(D_ / 64, M_ / 64), 256, 0, stream>>>(
        Hwb, vWT, M_, E_, E_, vb, nullptr, curR, curI, out);
  } else {                     // interleaved complex64 world
    gemm64<2><<<dim3(E_ / 64, M_ / 64), 256, 0, stream>>>(
        Hwb, vWT, M_, E_, E_, vb, nullptr, curR, curI, out);
  }
}